// Round 1
// baseline (109.025 us; speedup 1.0000x reference)
//
#include <hip/hip_runtime.h>
#include <math.h>

#define BB 16
#define NBB 512
#define BSS 128
#define KK 32
#define NBLK (BB*NBB)        // 8192 blocks total
#define NELEM (BB*NBB*BSS)   // 1048576 elements

// ws float layout:
//   [0      .. 8192)  bceS   per-block sum of BCE terms (sup-masked)
//   [8192   ..16384)  bceC   per-block count of sup
//   [16384  ..24576)  Svp    per-block sum of vld*p
//   [24576  ..32768)  Cv     per-block count of vld
//   [32768  ..40960)  Sup    per-block sum of unc*p
//   [40960  ..49152)  Sup2   per-block sum of unc*p*p
//   [49152  ..57344)  Cu     per-block count of unc
//   [57344  ..57408)  P      per-batch partials [16][4]: loss_b, nunc_b, bceS_b, bceC_b
//   [57600]           flag   mask-encoding detection (1 = 1-byte bool, 0 = 4-byte)

// Detect whether the bool masks are passed as 1-byte or 4-byte elements.
// A nonzero byte at offset % 4 == 1 can only happen for byte-packed bools
// (~10% true density => certain within 16K sampled positions). int32 0/1 and
// float 0.0/1.0 have a zero byte there.
__global__ void detect_kernel(const unsigned char* __restrict__ sup, int* __restrict__ flag) {
    __shared__ int found;
    if (threadIdx.x == 0) found = 0;
    __syncthreads();
    int local = 0;
    for (int j = threadIdx.x; j < 16384; j += blockDim.x) {
        if (sup[4 * j + 1] != 0) local = 1;
    }
    if (local) atomicOr(&found, 1);
    __syncthreads();
    if (threadIdx.x == 0) *flag = found;
}

__global__ __launch_bounds__(64) void blockstats_kernel(
    const float* __restrict__ logits, const float* __restrict__ targets,
    const unsigned char* __restrict__ sup_b, const unsigned char* __restrict__ ign_b,
    const int* __restrict__ flag, float* __restrict__ W)
{
    const int bid = blockIdx.x;    // 0..8191  (= b*NBB + i)
    const int t   = threadIdx.x;   // 0..63
    const bool byteMode = (*flag != 0);
    const int* sup_w = (const int*)sup_b;
    const int* ign_w = (const int*)ign_b;

    float bs = 0.f, bc = 0.f, svp = 0.f, cv = 0.f, su = 0.f, su2 = 0.f, cu = 0.f;
    #pragma unroll
    for (int r = 0; r < 2; ++r) {
        const int e = bid * BSS + t + r * 64;
        const float x  = logits[e];
        const float tg = targets[e];
        bool s, g;
        if (byteMode) { s = (sup_b[e] != 0); g = (ign_b[e] != 0); }
        else          { s = (sup_w[e] != 0); g = (ign_w[e] != 0); }
        const float p = 1.0f / (1.0f + expf(-x));
        if (s) {
            const float per = fmaxf(x, 0.0f) - x * tg + log1pf(expf(-fabsf(x)));
            bs += per; bc += 1.0f;
        }
        if (!g) {                  // valid neighbor node
            svp += p; cv += 1.0f;
            if (!s) {              // uncertain query node
                su += p; su2 += p * p; cu += 1.0f;
            }
        }
    }
    // wave-64 reduction
    for (int off = 32; off > 0; off >>= 1) {
        bs  += __shfl_down(bs,  off);
        bc  += __shfl_down(bc,  off);
        svp += __shfl_down(svp, off);
        cv  += __shfl_down(cv,  off);
        su  += __shfl_down(su,  off);
        su2 += __shfl_down(su2, off);
        cu  += __shfl_down(cu,  off);
    }
    if (t == 0) {
        W[bid]          = bs;
        W[8192  + bid]  = bc;
        W[16384 + bid]  = svp;
        W[24576 + bid]  = cv;
        W[32768 + bid]  = su;
        W[40960 + bid]  = su2;
        W[49152 + bid]  = cu;
    }
}

__global__ __launch_bounds__(256) void batch_kernel(
    const int* __restrict__ kv_idx, const int* __restrict__ kv_nb,
    const float* __restrict__ W, float* __restrict__ P)
{
    const int b = blockIdx.x;      // batch
    const int t = threadIdx.x;     // 0..255
    const float* bceS = W;
    const float* bceC = W + 8192;
    const float* Svp  = W + 16384;
    const float* Cv   = W + 24576;
    const float* Sup  = W + 32768;
    const float* Sup2 = W + 40960;
    const float* Cu   = W + 49152;

    float loss_b = 0.f, nunc_b = 0.f, bs = 0.f, bc = 0.f;
    for (int i = t; i < NBB; i += 256) {
        const int gb = b * NBB + i;
        bs += bceS[gb];
        bc += bceC[gb];
        const int knb = kv_nb[gb];
        const int* idx = kv_idx + (size_t)gb * KK;
        float cnt = 0.f, psum = 0.f;
        for (int k = 0; k < knb; ++k) {
            const int j = idx[k];
            cnt  += Cv[b * NBB + j];
            psum += Svp[b * NBB + j];
        }
        const float cu = Cu[gb];
        const bool ok = (cu > 0.0f) && (knb > 0) && (cnt > 0.0f);
        if (ok) {
            const float m  = psum / fmaxf(cnt, 1.0f);
            const float sq = Sup2[gb] - 2.0f * m * Sup[gb] + m * m * cu;
            loss_b += sq;
            nunc_b += cu;
        }
    }
    // 256-thread reduction: wave shuffle then LDS across 4 waves
    for (int off = 32; off > 0; off >>= 1) {
        loss_b += __shfl_down(loss_b, off);
        nunc_b += __shfl_down(nunc_b, off);
        bs     += __shfl_down(bs,     off);
        bc     += __shfl_down(bc,     off);
    }
    __shared__ float sm[4][4];
    const int wid = t >> 6, lane = t & 63;
    if (lane == 0) { sm[wid][0] = loss_b; sm[wid][1] = nunc_b; sm[wid][2] = bs; sm[wid][3] = bc; }
    __syncthreads();
    if (t == 0) {
        float l = 0.f, n = 0.f, s = 0.f, c = 0.f;
        for (int w = 0; w < 4; ++w) { l += sm[w][0]; n += sm[w][1]; s += sm[w][2]; c += sm[w][3]; }
        P[b * 4 + 0] = l;
        P[b * 4 + 1] = n;
        P[b * 4 + 2] = s;
        P[b * 4 + 3] = c;
    }
}

__global__ void final_kernel(const float* __restrict__ P, float* __restrict__ out) {
    if (threadIdx.x == 0 && blockIdx.x == 0) {
        float gsum = 0.f, nval = 0.f, bs = 0.f, bc = 0.f;
        for (int b = 0; b < BB; ++b) {
            const float l = P[b * 4 + 0];
            const float n = P[b * 4 + 1];
            bs += P[b * 4 + 2];
            bc += P[b * 4 + 3];
            if (n > 0.0f) { gsum += l / fmaxf(n, 1.0f); nval += 1.0f; }
        }
        const float loss_sup   = bs / fmaxf(bc, 1.0f);
        const float loss_graph = gsum / fmaxf(nval, 1.0f);
        out[0] = loss_sup + 0.3f * loss_graph;
    }
}

extern "C" void kernel_launch(void* const* d_in, const int* in_sizes, int n_in,
                              void* d_out, int out_size, void* d_ws, size_t ws_size,
                              hipStream_t stream) {
    (void)in_sizes; (void)n_in; (void)out_size; (void)ws_size;
    const float* logits  = (const float*)d_in[0];
    const float* targets = (const float*)d_in[1];
    const unsigned char* supm = (const unsigned char*)d_in[2];
    const unsigned char* ignm = (const unsigned char*)d_in[3];
    const int* kv_idx = (const int*)d_in[4];
    const int* kv_nb  = (const int*)d_in[5];
    float* W = (float*)d_ws;
    float* P = W + 57344;
    int* flag = (int*)(W + 57600);
    float* out = (float*)d_out;

    hipLaunchKernelGGL(detect_kernel, dim3(1), dim3(256), 0, stream, supm, flag);
    hipLaunchKernelGGL(blockstats_kernel, dim3(NBLK), dim3(64), 0, stream,
                       logits, targets, supm, ignm, flag, W);
    hipLaunchKernelGGL(batch_kernel, dim3(BB), dim3(256), 0, stream, kv_idx, kv_nb, W, P);
    hipLaunchKernelGGL(final_kernel, dim3(1), dim3(64), 0, stream, P, out);
}

// Round 2
// 105.009 us; speedup vs baseline: 1.0382x; 1.0382x over previous
//
#include <hip/hip_runtime.h>
#include <math.h>

#define BB 16
#define NBB 512
#define BSS 128
#define KK 32
#define NBLK (BB*NBB)        // 8192 query blocks

// W (float) layout:
//   [0     .. 8192)   Svp   per-block sum of vld*p
//   [8192  ..16384)   Cv    per-block count of vld
//   [16384 ..24576)   Sup   per-block sum of unc*p
//   [24576 ..32768)   Sup2  per-block sum of unc*p^2
//   [32768 ..40960)   Cu    per-block count of unc
//   [40960 ..49152)   bceS  per-block sum of BCE terms (sup-masked)
//   [49152 ..57344)   bceC  per-block count of sup
//   [57344 ..57378)   P     accumulators: [16]x{loss,nunc} then bs, bc
//   [57384]           ticket (int)

// Kernel 1: per-query-block stats. One wave per query block (4 per 256-thread
// workgroup). Mask encoding (1-byte bool vs 4-byte) detected per block by
// sampling 1024 bytes at offset%4==1 in the first 4KB of sup (nonzero there
// only possible for byte-packed bools; ~10% density => miss prob ~1e-47).
__global__ __launch_bounds__(256) void stats_kernel(
    const float* __restrict__ logits, const float* __restrict__ targets,
    const unsigned char* __restrict__ sup_b, const unsigned char* __restrict__ ign_b,
    float* __restrict__ W)
{
    const int t = threadIdx.x;
    __shared__ int s_mode;
    if (t == 0) s_mode = 0;
    __syncthreads();
    int local = 0;
    #pragma unroll
    for (int r = 0; r < 4; ++r) {
        if (sup_b[4 * (t + 256 * r) + 1] != 0) local = 1;
    }
    if (local) atomicOr(&s_mode, 1);
    __syncthreads();
    const bool byteMode = (s_mode != 0);
    const int* sup_w = (const int*)sup_b;
    const int* ign_w = (const int*)ign_b;

    const int wv = t >> 6, lane = t & 63;
    const int qb = blockIdx.x * 4 + wv;       // global query-block id (b*NBB+i)

    float svp = 0.f, cv = 0.f, su = 0.f, su2 = 0.f, cu = 0.f, bs = 0.f, bc = 0.f;
    #pragma unroll
    for (int r = 0; r < 2; ++r) {
        const int e = qb * BSS + lane + r * 64;
        const float x  = logits[e];
        const float tg = targets[e];
        bool s, g;
        if (byteMode) { s = (sup_b[e] != 0); g = (ign_b[e] != 0); }
        else          { s = (sup_w[e] != 0); g = (ign_w[e] != 0); }
        const float p = 1.0f / (1.0f + expf(-x));
        if (s) {
            bs += fmaxf(x, 0.0f) - x * tg + log1pf(expf(-fabsf(x)));
            bc += 1.0f;
        }
        if (!g) {
            svp += p; cv += 1.0f;
            if (!s) { su += p; su2 += p * p; cu += 1.0f; }
        }
    }
    #pragma unroll
    for (int off = 32; off > 0; off >>= 1) {
        svp += __shfl_down(svp, off);
        cv  += __shfl_down(cv,  off);
        su  += __shfl_down(su,  off);
        su2 += __shfl_down(su2, off);
        cu  += __shfl_down(cu,  off);
        bs  += __shfl_down(bs,  off);
        bc  += __shfl_down(bc,  off);
    }
    if (lane == 0) {
        W[qb]           = svp;
        W[8192  + qb]   = cv;
        W[16384 + qb]   = su;
        W[24576 + qb]   = su2;
        W[32768 + qb]   = cu;
        W[40960 + qb]   = bs;
        W[49152 + qb]   = bc;
    }
    // zero the accumulators + ticket for kernel 2 (stream-ordered after us)
    if (blockIdx.x == 0 && t == 0) {
        #pragma unroll
        for (int i = 0; i < 34; ++i) W[57344 + i] = 0.0f;
        *((int*)(W + 57384)) = 0;
    }
}

// Kernel 2: neighbor aggregation + last-block finalize.
// 128 blocks x 64 threads: block (b, slice) covers i = slice*64 + lane.
__global__ __launch_bounds__(64) void graph_kernel(
    const int* __restrict__ kv_idx, const int* __restrict__ kv_nb,
    float* __restrict__ W, float* __restrict__ out)
{
    const int t  = threadIdx.x;
    const int b  = blockIdx.x >> 3;
    const int i  = ((blockIdx.x & 7) << 6) + t;
    const int gb = b * NBB + i;

    const float* Svp  = W;
    const float* Cv   = W + 8192;
    const float* Sup  = W + 16384;
    const float* Sup2 = W + 24576;
    const float* Cu   = W + 32768;
    const float* bceS = W + 40960;
    const float* bceC = W + 49152;
    float* P     = W + 57344;
    int* ticket  = (int*)(W + 57384);

    float bs = bceS[gb];
    float bc = bceC[gb];
    const int knb = kv_nb[gb];
    const int* idx = kv_idx + (size_t)gb * KK;
    float cnt = 0.f, psum = 0.f;
    for (int k = 0; k < knb; ++k) {
        const int j = idx[k];
        cnt  += Cv[b * NBB + j];
        psum += Svp[b * NBB + j];
    }
    const float cu = Cu[gb];
    float loss = 0.f, nunc = 0.f;
    if (cu > 0.0f && knb > 0 && cnt > 0.0f) {
        const float m = psum / fmaxf(cnt, 1.0f);
        loss = Sup2[gb] - 2.0f * m * Sup[gb] + m * m * cu;
        nunc = cu;
    }
    #pragma unroll
    for (int off = 32; off > 0; off >>= 1) {
        loss += __shfl_down(loss, off);
        nunc += __shfl_down(nunc, off);
        bs   += __shfl_down(bs,   off);
        bc   += __shfl_down(bc,   off);
    }
    if (t == 0) {
        atomicAdd(&P[b * 2 + 0], loss);
        atomicAdd(&P[b * 2 + 1], nunc);
        atomicAdd(&P[32], bs);
        atomicAdd(&P[33], bc);
        __threadfence();
        const int rank = atomicAdd(ticket, 1);
        if (rank == 127) {            // last block: finalize
            __threadfence();
            float gsum = 0.f, nval = 0.f;
            for (int b2 = 0; b2 < BB; ++b2) {
                const float l = atomicAdd(&P[b2 * 2 + 0], 0.0f);  // coherent read
                const float n = atomicAdd(&P[b2 * 2 + 1], 0.0f);
                if (n > 0.0f) { gsum += l / fmaxf(n, 1.0f); nval += 1.0f; }
            }
            const float tbs = atomicAdd(&P[32], 0.0f);
            const float tbc = atomicAdd(&P[33], 0.0f);
            out[0] = tbs / fmaxf(tbc, 1.0f) + 0.3f * (gsum / fmaxf(nval, 1.0f));
        }
    }
}

extern "C" void kernel_launch(void* const* d_in, const int* in_sizes, int n_in,
                              void* d_out, int out_size, void* d_ws, size_t ws_size,
                              hipStream_t stream) {
    (void)in_sizes; (void)n_in; (void)out_size; (void)ws_size;
    const float* logits  = (const float*)d_in[0];
    const float* targets = (const float*)d_in[1];
    const unsigned char* supm = (const unsigned char*)d_in[2];
    const unsigned char* ignm = (const unsigned char*)d_in[3];
    const int* kv_idx = (const int*)d_in[4];
    const int* kv_nb  = (const int*)d_in[5];
    float* W   = (float*)d_ws;
    float* out = (float*)d_out;

    hipLaunchKernelGGL(stats_kernel, dim3(NBLK / 4), dim3(256), 0, stream,
                       logits, targets, supm, ignm, W);
    hipLaunchKernelGGL(graph_kernel, dim3(128), dim3(64), 0, stream,
                       kv_idx, kv_nb, W, out);
}

// Round 3
// 102.864 us; speedup vs baseline: 1.0599x; 1.0208x over previous
//
#include <hip/hip_runtime.h>
#include <math.h>

#define BB 16
#define NBB 512
#define BSS 128
#define KK 32
#define NBLK (BB*NBB)        // 8192 query blocks
#define STATS_GRID 1024      // 1,048,576 elems / (256 thr * 4 elem)

// W (float) layout:
//   [0     .. 8192)   Svp   per-block sum of vld*p
//   [8192  ..16384)   Cv    per-block count of vld
//   [16384 ..24576)   Sup   per-block sum of unc*p
//   [24576 ..32768)   Sup2  per-block sum of unc*p^2
//   [32768 ..40960)   Cu    per-block count of unc
//   [40960 ..49152)   bceS  per-block sum of BCE terms (sup-masked)
//   [49152 ..57344)   bceC  per-block count of sup
//   [57344 ..57378)   P     accumulators: [16]x{loss,nunc} then bs, bc
//   [57384]           ticket (int)

// Kernel 1: per-query-block stats, vectorized. 1024 blocks x 256 threads;
// each thread handles 4 contiguous elements (float4), so each 32-lane group
// covers exactly one 128-element query block. Mask encoding (1-byte bool vs
// 4-byte word) detected per block by sampling 1024 bytes at offset%4==1 in
// the first 4KB of sup (nonzero there only possible for byte-packed bools;
// ~10% true density => miss prob 0.9^1024 ~ 1e-47).
__global__ __launch_bounds__(256) void stats_kernel(
    const float* __restrict__ logits, const float* __restrict__ targets,
    const unsigned char* __restrict__ sup_b, const unsigned char* __restrict__ ign_b,
    float* __restrict__ W)
{
    const int t = threadIdx.x;
    __shared__ int s_mode;
    if (t == 0) s_mode = 0;
    __syncthreads();
    int local = 0;
    #pragma unroll
    for (int r = 0; r < 4; ++r) {
        if (sup_b[4 * (t + 256 * r) + 1] != 0) local = 1;
    }
    if (local) atomicOr(&s_mode, 1);
    __syncthreads();
    const bool byteMode = (s_mode != 0);

    const int gid = blockIdx.x * 256 + t;          // float4 index
    const float4 x4 = ((const float4*)logits)[gid];
    const float4 t4 = ((const float4*)targets)[gid];
    bool s[4], g[4];
    if (byteMode) {
        const unsigned int sm = ((const unsigned int*)sup_b)[gid];
        const unsigned int gm = ((const unsigned int*)ign_b)[gid];
        #pragma unroll
        for (int j = 0; j < 4; ++j) {
            s[j] = ((sm >> (8 * j)) & 0xffu) != 0;
            g[j] = ((gm >> (8 * j)) & 0xffu) != 0;
        }
    } else {
        const int4 sm = ((const int4*)sup_b)[gid];
        const int4 gm = ((const int4*)ign_b)[gid];
        s[0] = sm.x != 0; s[1] = sm.y != 0; s[2] = sm.z != 0; s[3] = sm.w != 0;
        g[0] = gm.x != 0; g[1] = gm.y != 0; g[2] = gm.z != 0; g[3] = gm.w != 0;
    }
    const float xs[4] = {x4.x, x4.y, x4.z, x4.w};
    const float ts[4] = {t4.x, t4.y, t4.z, t4.w};

    float svp = 0.f, cv = 0.f, su = 0.f, su2 = 0.f, cu = 0.f, bs = 0.f, bc = 0.f;
    #pragma unroll
    for (int j = 0; j < 4; ++j) {
        const float x = xs[j];
        const float p = 1.0f / (1.0f + expf(-x));
        if (s[j]) {
            bs += fmaxf(x, 0.0f) - x * ts[j] + log1pf(expf(-fabsf(x)));
            bc += 1.0f;
        }
        if (!g[j]) {
            svp += p; cv += 1.0f;
            if (!s[j]) { su += p; su2 += p * p; cu += 1.0f; }
        }
    }
    // width-32 group reduction: each 32-lane group = one query block
    #pragma unroll
    for (int off = 16; off > 0; off >>= 1) {
        svp += __shfl_down(svp, off, 32);
        cv  += __shfl_down(cv,  off, 32);
        su  += __shfl_down(su,  off, 32);
        su2 += __shfl_down(su2, off, 32);
        cu  += __shfl_down(cu,  off, 32);
        bs  += __shfl_down(bs,  off, 32);
        bc  += __shfl_down(bc,  off, 32);
    }
    if ((t & 31) == 0) {
        const int qb = blockIdx.x * 8 + (t >> 5);  // global query-block id
        W[qb]           = svp;
        W[8192  + qb]   = cv;
        W[16384 + qb]   = su;
        W[24576 + qb]   = su2;
        W[32768 + qb]   = cu;
        W[40960 + qb]   = bs;
        W[49152 + qb]   = bc;
    }
    // zero the accumulators + ticket for kernel 2 (stream-ordered after us)
    if (blockIdx.x == 0 && t == 0) {
        #pragma unroll
        for (int i = 0; i < 34; ++i) W[57344 + i] = 0.0f;
        *((int*)(W + 57384)) = 0;
    }
}

// Kernel 2: neighbor aggregation + last-block finalize.
// 128 blocks x 64 threads: block (b, slice) covers i = slice*64 + lane.
__global__ __launch_bounds__(64) void graph_kernel(
    const int* __restrict__ kv_idx, const int* __restrict__ kv_nb,
    float* __restrict__ W, float* __restrict__ out)
{
    const int t  = threadIdx.x;
    const int b  = blockIdx.x >> 3;
    const int i  = ((blockIdx.x & 7) << 6) + t;
    const int gb = b * NBB + i;

    const float* Svp  = W;
    const float* Cv   = W + 8192;
    const float* Sup  = W + 16384;
    const float* Sup2 = W + 24576;
    const float* Cu   = W + 32768;
    const float* bceS = W + 40960;
    const float* bceC = W + 49152;
    float* P     = W + 57344;
    int* ticket  = (int*)(W + 57384);

    float bs = bceS[gb];
    float bc = bceC[gb];
    const int knb = kv_nb[gb];
    const int* idx = kv_idx + (size_t)gb * KK;
    float cnt = 0.f, psum = 0.f;
    for (int k = 0; k < knb; ++k) {
        const int j = idx[k];
        cnt  += Cv[b * NBB + j];
        psum += Svp[b * NBB + j];
    }
    const float cu = Cu[gb];
    float loss = 0.f, nunc = 0.f;
    if (cu > 0.0f && knb > 0 && cnt > 0.0f) {
        const float m = psum / fmaxf(cnt, 1.0f);
        loss = Sup2[gb] - 2.0f * m * Sup[gb] + m * m * cu;
        nunc = cu;
    }
    #pragma unroll
    for (int off = 32; off > 0; off >>= 1) {
        loss += __shfl_down(loss, off);
        nunc += __shfl_down(nunc, off);
        bs   += __shfl_down(bs,   off);
        bc   += __shfl_down(bc,   off);
    }
    if (t == 0) {
        atomicAdd(&P[b * 2 + 0], loss);
        atomicAdd(&P[b * 2 + 1], nunc);
        atomicAdd(&P[32], bs);
        atomicAdd(&P[33], bc);
        __threadfence();
        const int rank = atomicAdd(ticket, 1);
        if (rank == 127) {            // last block: finalize
            __threadfence();
            float gsum = 0.f, nval = 0.f;
            for (int b2 = 0; b2 < BB; ++b2) {
                const float l = atomicAdd(&P[b2 * 2 + 0], 0.0f);  // coherent read
                const float n = atomicAdd(&P[b2 * 2 + 1], 0.0f);
                if (n > 0.0f) { gsum += l / fmaxf(n, 1.0f); nval += 1.0f; }
            }
            const float tbs = atomicAdd(&P[32], 0.0f);
            const float tbc = atomicAdd(&P[33], 0.0f);
            out[0] = tbs / fmaxf(tbc, 1.0f) + 0.3f * (gsum / fmaxf(nval, 1.0f));
        }
    }
}

extern "C" void kernel_launch(void* const* d_in, const int* in_sizes, int n_in,
                              void* d_out, int out_size, void* d_ws, size_t ws_size,
                              hipStream_t stream) {
    (void)in_sizes; (void)n_in; (void)out_size; (void)ws_size;
    const float* logits  = (const float*)d_in[0];
    const float* targets = (const float*)d_in[1];
    const unsigned char* supm = (const unsigned char*)d_in[2];
    const unsigned char* ignm = (const unsigned char*)d_in[3];
    const int* kv_idx = (const int*)d_in[4];
    const int* kv_nb  = (const int*)d_in[5];
    float* W   = (float*)d_ws;
    float* out = (float*)d_out;

    hipLaunchKernelGGL(stats_kernel, dim3(STATS_GRID), dim3(256), 0, stream,
                       logits, targets, supm, ignm, W);
    hipLaunchKernelGGL(graph_kernel, dim3(128), dim3(64), 0, stream,
                       kv_idx, kv_nb, W, out);
}